// Round 2
// baseline (882.928 us; speedup 1.0000x reference)
//
#include <hip/hip_runtime.h>
#include <hip/hip_bf16.h>
#include <math.h>

// GNO: h = lift(x); 4x [ h = gelu(h@(Wb + c0*Wq@M) + (bb + c0*bq@M)), M = k^T v ];
// out = h@proj. Associativity: (q k^T) v == q (k^T v); no softmax in between, so
// the [N,N] kernel matrix is never materialized: O(N^2 d) -> O(N d^2).
//
// Dtype-adaptive: a detector kernel classifies the input buffers (fp32 vs bf16)
// at runtime and both templated variants are launched; the mismatched variant
// early-exits (uniform branch). Output dtype follows input dtype.

#define NLAYER 4
#define NB 2
#define NN 4096
#define DD 64
#define RPB 64           // rows per block
#define NT 256           // threads per block
#define C0F (1.0f/32768.0f)  // scale/N = (1/8)/4096

typedef __hip_bfloat16 bf16;

__device__ __forceinline__ float b2f(const bf16 v) { return __bfloat162float(v); }

template <typename T> struct Acc;
template <> struct Acc<float> {
    static constexpr int tag = 0;
    static __device__ __forceinline__ float ld(const void* p, int i) { return ((const float*)p)[i]; }
    static __device__ __forceinline__ void st(void* p, int i, float v) { ((float*)p)[i] = v; }
};
template <> struct Acc<bf16> {
    static constexpr int tag = 1;
    static __device__ __forceinline__ float ld(const void* p, int i) { return b2f(((const bf16*)p)[i]); }
    static __device__ __forceinline__ void st(void* p, int i, float v) { ((bf16*)p)[i] = __float2bfloat16(v); }
};

__device__ __forceinline__ float gelu_exact(float x) {
    return 0.5f * x * (1.0f + erff(x * 0.70710678118654752f));
}

__device__ __forceinline__ void fma4v(float* a, float s, float4 w) {
    a[0] += s * w.x; a[1] += s * w.y; a[2] += s * w.z; a[3] += s * w.w;
}

// Classify input dtype: scan 8192 32-bit words of x. If data is bf16, the low
// uint16 of each word is an independent bf16 sample (exponent field clustered
// around the bias, ~99% hit). If data is fp32, the low 16 bits are low mantissa
// bits (uniform) -> ~17% hit. Writes flag: 1 = bf16, 0 = fp32.
__global__ void detect_kernel(const unsigned int* __restrict__ x, int* __restrict__ flag) {
    __shared__ int tot;
    const int t = threadIdx.x;
    if (t == 0) tot = 0;
    __syncthreads();
    int cnt = 0;
    for (int i = t; i < 8192; i += NT) {
        unsigned u = x[i] & 0xFFFFu;
        int e = (u >> 7) & 0xFF;
        cnt += (u == 0u || (e >= 100 && e <= 142)) ? 1 : 0;
    }
    atomicAdd(&tot, cnt);
    __syncthreads();
    if (t == 0) flag[0] = (tot > 4915) ? 1 : 0;   // 60% of 8192
}

// Given this thread's 16 new-h values (row r = t>>2, cols cbase..cbase+15) in
// regs, and Wk/Wv staged in LDS, accumulate the NEXT layer's M = k^T v partial
// for this block and atomicAdd into global Mout. Two 32-row halves (LDS fit).
__device__ void accum_M(const float (*wk)[DD], const float (*wv)[DD],
                        float (*hn)[DD + 1], float (*ks)[DD + 1], float (*vs)[DD + 1],
                        const float* bks, const float* bvs,
                        const float* hvnew, int t, float* Mout)
{
    const int r = t >> 2;
    const int cbase = (t & 3) << 4;
    const int rl = t >> 3;           // 0..31: row for k/v compute (8 threads/row)
    const int c8 = (t & 7) << 3;     // 8-col base for k/v compute
    const int e0 = (t >> 4) << 2;    // M-accum: 4x4 tile
    const int c0 = (t & 15) << 2;

    float m[4][4];
    #pragma unroll
    for (int a = 0; a < 4; a++)
        #pragma unroll
        for (int b = 0; b < 4; b++) m[a][b] = 0.0f;

    #pragma unroll
    for (int half = 0; half < 2; ++half) {
        if ((r >> 5) == half) {
            #pragma unroll
            for (int j = 0; j < 16; j++) hn[r & 31][cbase + j] = hvnew[j];
        }
        __syncthreads();
        {
            float hrow[DD];
            #pragma unroll
            for (int d = 0; d < DD; d++) hrow[d] = hn[rl][d];
            float ak[8], av[8];
            #pragma unroll
            for (int j = 0; j < 8; j++) { ak[j] = bks[c8 + j]; av[j] = bvs[c8 + j]; }
            #pragma unroll
            for (int d = 0; d < DD; d++) {
                float hv = hrow[d];
                const float4* wk4 = (const float4*)&wk[d][c8];
                const float4* wv4 = (const float4*)&wv[d][c8];
                fma4v(ak + 0, hv, wk4[0]); fma4v(ak + 4, hv, wk4[1]);
                fma4v(av + 0, hv, wv4[0]); fma4v(av + 4, hv, wv4[1]);
            }
            #pragma unroll
            for (int j = 0; j < 8; j++) { ks[rl][c8 + j] = ak[j]; vs[rl][c8 + j] = av[j]; }
        }
        __syncthreads();
        #pragma unroll 4
        for (int n = 0; n < 32; n++) {
            float ke[4], vc[4];
            #pragma unroll
            for (int a = 0; a < 4; a++) { ke[a] = ks[n][e0 + a]; vc[a] = vs[n][c0 + a]; }
            #pragma unroll
            for (int a = 0; a < 4; a++)
                #pragma unroll
                for (int b = 0; b < 4; b++) m[a][b] += ke[a] * vc[b];
        }
        __syncthreads();
    }
    #pragma unroll
    for (int a = 0; a < 4; a++)
        #pragma unroll
        for (int b = 0; b < 4; b++)
            atomicAdd(&Mout[(e0 + a) * DD + (c0 + b)], m[a][b]);
}

template <typename T>
__global__ __launch_bounds__(NT) void lift_kernel(
    const int* __restrict__ flag,
    const void* __restrict__ x,
    const void* __restrict__ lw_g, const void* __restrict__ lb_g,
    const void* __restrict__ kw_g, const void* __restrict__ kb_g,
    const void* __restrict__ vw_g, const void* __restrict__ vb_g,
    float* __restrict__ h, float* __restrict__ Mout)
{
    if (flag[0] != Acc<T>::tag) return;   // uniform across grid

    __shared__ alignas(16) float wkb[DD][DD];
    __shared__ alignas(16) float wvb[DD][DD];
    __shared__ float hn[32][DD + 1];
    __shared__ float ks[32][DD + 1];
    __shared__ float vs[32][DD + 1];
    __shared__ float bks[DD], bvs[DD];

    const int t = threadIdx.x;
    const int row0 = blockIdx.x * RPB;
    const int b = row0 >> 12;
    const int r = t >> 2;
    const int cbase = (t & 3) << 4;

    for (int i = t; i < DD * DD; i += NT) {
        wkb[i >> 6][i & 63] = Acc<T>::ld(kw_g, i);
        wvb[i >> 6][i & 63] = Acc<T>::ld(vw_g, i);
    }
    if (t < DD) { bks[t] = Acc<T>::ld(kb_g, t); bvs[t] = Acc<T>::ld(vb_g, t); }

    float hvnew[16];
    {
        const int gr = row0 + r;
        float x0 = Acc<T>::ld(x, gr * 3 + 0);
        float x1 = Acc<T>::ld(x, gr * 3 + 1);
        float x2 = Acc<T>::ld(x, gr * 3 + 2);
        #pragma unroll
        for (int j = 0; j < 16; j++) {
            int c = cbase + j;
            hvnew[j] = Acc<T>::ld(lb_g, c) + x0 * Acc<T>::ld(lw_g, c)
                     + x1 * Acc<T>::ld(lw_g, DD + c) + x2 * Acc<T>::ld(lw_g, 2 * DD + c);
        }
        float4* h4o = (float4*)(h + (size_t)gr * DD + cbase);
        #pragma unroll
        for (int j4 = 0; j4 < 4; j4++)
            h4o[j4] = make_float4(hvnew[4 * j4], hvnew[4 * j4 + 1],
                                  hvnew[4 * j4 + 2], hvnew[4 * j4 + 3]);
    }
    // first __syncthreads inside accum_M covers the staging above
    accum_M(wkb, wvb, hn, ks, vs, bks, bvs, hvnew, t, Mout + b * DD * DD);
}

template <typename T>
__global__ __launch_bounds__(NT) void layer_kernel(
    const int* __restrict__ flag,
    float* __restrict__ h,
    const float* __restrict__ Min,
    const void* __restrict__ wq_g, const void* __restrict__ bq_g,
    const void* __restrict__ wb_g, const void* __restrict__ bb_g,
    const void* __restrict__ kw_g, const void* __restrict__ kb_g,
    const void* __restrict__ vw_g, const void* __restrict__ vb_g,
    float* __restrict__ Mout,
    const void* __restrict__ pw_g, const void* __restrict__ pb_g,
    void* __restrict__ out, int is_last)
{
    if (flag[0] != Acc<T>::tag) return;   // uniform across grid

    __shared__ alignas(16) float buf1[DD][DD];  // weff, then Wk_next
    __shared__ alignas(16) float buf2[DD][DD];  // M_i,  then Wv_next
    __shared__ float hn[32][DD + 1];
    __shared__ float ks[32][DD + 1];
    __shared__ float vs[32][DD + 1];
    __shared__ float beff[DD];
    __shared__ float bks[DD], bvs[DD];

    const int t = threadIdx.x;
    const int row0 = blockIdx.x * RPB;
    const int b = row0 >> 12;
    const int r = t >> 2;
    const int cbase = (t & 3) << 4;

    for (int i = t; i < DD * DD; i += NT) buf2[i >> 6][i & 63] = Min[b * DD * DD + i];
    __syncthreads();

    // weff[din][c] = Wb[din][c] + C0 * sum_e Wq[din][e] * M[e][c]
    {
        const int din = r;
        float wqrow[DD];
        #pragma unroll
        for (int e = 0; e < DD; e++) wqrow[e] = Acc<T>::ld(wq_g, din * DD + e);
        float acc[16];
        #pragma unroll
        for (int j = 0; j < 16; j++) acc[j] = 0.0f;
        #pragma unroll
        for (int e = 0; e < DD; e++) {
            float a = wqrow[e];
            const float4* m4 = (const float4*)&buf2[e][cbase];
            fma4v(acc + 0, a, m4[0]); fma4v(acc + 4, a, m4[1]);
            fma4v(acc + 8, a, m4[2]); fma4v(acc + 12, a, m4[3]);
        }
        #pragma unroll
        for (int j = 0; j < 16; j++)
            buf1[din][cbase + j] = Acc<T>::ld(wb_g, din * DD + cbase + j) + C0F * acc[j];
        if (t < DD) {
            float s = 0.0f;
            for (int e = 0; e < DD; e++) s += Acc<T>::ld(bq_g, e) * buf2[e][t];
            beff[t] = Acc<T>::ld(bb_g, t) + C0F * s;
        }
    }
    __syncthreads();

    // h' = gelu(h @ weff + beff)
    float hvnew[16];
    {
        float hrow[DD];
        const float4* h4 = (const float4*)(h + (size_t)(row0 + r) * DD);
        #pragma unroll
        for (int jj = 0; jj < 16; jj++) {
            float4 tmp = h4[jj];
            hrow[4 * jj] = tmp.x; hrow[4 * jj + 1] = tmp.y;
            hrow[4 * jj + 2] = tmp.z; hrow[4 * jj + 3] = tmp.w;
        }
        float acc[16];
        #pragma unroll
        for (int j = 0; j < 16; j++) acc[j] = beff[cbase + j];
        #pragma unroll
        for (int d = 0; d < DD; d++) {
            float hv = hrow[d];
            const float4* w4 = (const float4*)&buf1[d][cbase];
            fma4v(acc + 0, hv, w4[0]); fma4v(acc + 4, hv, w4[1]);
            fma4v(acc + 8, hv, w4[2]); fma4v(acc + 12, hv, w4[3]);
        }
        #pragma unroll
        for (int j = 0; j < 16; j++) hvnew[j] = gelu_exact(acc[j]);
    }

    if (is_last) {
        float p = 0.0f;
        #pragma unroll
        for (int j = 0; j < 16; j++) p += hvnew[j] * Acc<T>::ld(pw_g, cbase + j);
        p += __shfl_xor(p, 1);
        p += __shfl_xor(p, 2);
        if ((t & 3) == 0) Acc<T>::st(out, row0 + r, p + Acc<T>::ld(pb_g, 0));
        return;
    }

    {
        float4* h4o = (float4*)(h + (size_t)(row0 + r) * DD + cbase);
        #pragma unroll
        for (int j4 = 0; j4 < 4; j4++)
            h4o[j4] = make_float4(hvnew[4 * j4], hvnew[4 * j4 + 1],
                                  hvnew[4 * j4 + 2], hvnew[4 * j4 + 3]);
    }
    __syncthreads();  // all weff/buf2 reads done before re-staging

    for (int i = t; i < DD * DD; i += NT) {
        buf1[i >> 6][i & 63] = Acc<T>::ld(kw_g, i);
        buf2[i >> 6][i & 63] = Acc<T>::ld(vw_g, i);
    }
    if (t < DD) { bks[t] = Acc<T>::ld(kb_g, t); bvs[t] = Acc<T>::ld(vb_g, t); }

    accum_M(buf1, buf2, hn, ks, vs, bks, bvs, hvnew, t, Mout + b * DD * DD);
}

template <typename T>
static void launch_pipeline(const int* flag, void* const* d_in, void* d_out,
                            float* h, float* M, hipStream_t stream)
{
    const void* x    = d_in[0];
    const void* lw   = d_in[1];
    const void* lb   = d_in[2];
    const void* blkw = d_in[3];
    const void* blkb = d_in[4];
    const void* qw   = d_in[5];
    const void* qb   = d_in[6];
    const void* kw   = d_in[7];
    const void* kb   = d_in[8];
    const void* vw   = d_in[9];
    const void* vb   = d_in[10];
    const void* pw   = d_in[11];
    const void* pb   = d_in[12];

    const int grid = NB * NN / RPB;  // 128 blocks
    const int esz = (Acc<T>::tag == 1) ? 2 : 4;   // element size of inputs

    lift_kernel<T><<<grid, NT, 0, stream>>>(flag, x, lw, lb, kw, kb, vw, vb, h, M);
    for (int i = 0; i < NLAYER; i++) {
        const int last = (i == NLAYER - 1);
        const char* kwp = last ? nullptr : ((const char*)kw + (size_t)(i + 1) * DD * DD * esz);
        const char* kbp = last ? nullptr : ((const char*)kb + (size_t)(i + 1) * DD * esz);
        const char* vwp = last ? nullptr : ((const char*)vw + (size_t)(i + 1) * DD * DD * esz);
        const char* vbp = last ? nullptr : ((const char*)vb + (size_t)(i + 1) * DD * esz);
        layer_kernel<T><<<grid, NT, 0, stream>>>(
            flag, h, M + i * NB * DD * DD,
            (const char*)qw + (size_t)i * DD * DD * esz, (const char*)qb + (size_t)i * DD * esz,
            (const char*)blkw + (size_t)i * DD * DD * esz, (const char*)blkb + (size_t)i * DD * esz,
            kwp, kbp, vwp, vbp,
            last ? nullptr : (M + (i + 1) * NB * DD * DD),
            pw, pb, d_out, last);
    }
}

extern "C" void kernel_launch(void* const* d_in, const int* in_sizes, int n_in,
                              void* d_out, int out_size, void* d_ws, size_t ws_size,
                              hipStream_t stream)
{
    float* h = (float*)d_ws;                                      // [2][4096][64] fp32
    float* M = (float*)((char*)d_ws + (size_t)NB * NN * DD * 4);  // [4][2][64][64] fp32
    int* flag = (int*)(M + (size_t)NLAYER * NB * DD * DD);

    hipMemsetAsync(M, 0, (size_t)NLAYER * NB * DD * DD * sizeof(float), stream);
    detect_kernel<<<1, NT, 0, stream>>>((const unsigned int*)d_in[0], flag);

    launch_pipeline<float>(flag, d_in, d_out, h, M, stream);
    launch_pipeline<bf16>(flag, d_in, d_out, h, M, stream);
}

// Round 3
// 275.988 us; speedup vs baseline: 3.1992x; 3.1992x over previous
//
#include <hip/hip_runtime.h>
#include <hip/hip_bf16.h>
#include <math.h>

// GNO: h = lift(x); 4x [ h = gelu(h@(Wb + c0*Wq@M) + (bb + c0*bq@M)) ], M = k^T v;
// out = h@proj.  Two algebraic collapses:
//  (1) (q k^T) v == q (k^T v): never materialize the [N,N] kernel.
//  (2) M = (hWk+bk)^T (hWv+bv) = Wk^T G Wv + (Wk^T s) bv^T + bk (s^T Wv) + N bk bv^T,
//      with G = h^T h (symmetric, 64x64) and s = h^T 1 (64).
// Blocks only atomically accumulate G,s; each consumer block rebuilds M in LDS.
// All matmul phases are 4x4-tile outer products (<=32 live floats/thread) to
// avoid the register spilling that dominated round 2 (VGPR=256, 160MB scratch
// traffic/dispatch).

#define NLAYER 4
#define NB 2
#define NN 4096
#define DD 64
#define RPB 32              // rows per block
#define NT 256              // threads per block
#define NGRID (NB*NN/RPB)   // 256 blocks -> one per CU
#define C0F (1.0f/32768.0f) // scale/N = (1/8)/4096
#define SHP 68              // padded LDS stride for sH (16B-aligned rows, no conflicts)

typedef __hip_bfloat16 bf16;

__device__ __forceinline__ float b2f(const bf16 v) { return __bfloat162float(v); }

template <typename T> struct Acc;
template <> struct Acc<float> {
    static constexpr int tag = 0;
    static __device__ __forceinline__ float ld(const void* p, int i) { return ((const float*)p)[i]; }
    static __device__ __forceinline__ void st(void* p, int i, float v) { ((float*)p)[i] = v; }
};
template <> struct Acc<bf16> {
    static constexpr int tag = 1;
    static __device__ __forceinline__ float ld(const void* p, int i) { return b2f(((const bf16*)p)[i]); }
    static __device__ __forceinline__ void st(void* p, int i, float v) { ((bf16*)p)[i] = __float2bfloat16(v); }
};

__device__ __forceinline__ float gelu_exact(float x) {
    return 0.5f * x * (1.0f + erff(x * 0.70710678118654752f));
}

// Classify input dtype from the raw bits of x (flag: 1 = bf16, 0 = fp32).
__global__ void detect_kernel(const unsigned int* __restrict__ x, int* __restrict__ flag) {
    __shared__ int tot;
    const int t = threadIdx.x;
    if (t == 0) tot = 0;
    __syncthreads();
    int cnt = 0;
    for (int i = t; i < 8192; i += NT) {
        unsigned u = x[i] & 0xFFFFu;
        int e = (u >> 7) & 0xFF;
        cnt += (u == 0u || (e >= 100 && e <= 142)) ? 1 : 0;
    }
    atomicAdd(&tot, cnt);
    __syncthreads();
    if (t == 0) flag[0] = (tot > 4915) ? 1 : 0;
}

// Accumulate G += sH^T sH (4x4 tile/thread) and s += column sums, via atomics.
__device__ __forceinline__ void accum_G(const float (*sH)[SHP], int t, int tr4, int tc4,
                                        float* __restrict__ Gout, float* __restrict__ sout)
{
    float m[4][4];
    #pragma unroll
    for (int a = 0; a < 4; a++)
        #pragma unroll
        for (int b = 0; b < 4; b++) m[a][b] = 0.0f;
    for (int n = 0; n < RPB; n++) {
        float4 he = *(const float4*)&sH[n][tr4];
        float4 hc = *(const float4*)&sH[n][tc4];
        float hea[4] = {he.x, he.y, he.z, he.w};
        float hca[4] = {hc.x, hc.y, hc.z, hc.w};
        #pragma unroll
        for (int a = 0; a < 4; a++)
            #pragma unroll
            for (int b = 0; b < 4; b++) m[a][b] += hea[a] * hca[b];
    }
    #pragma unroll
    for (int a = 0; a < 4; a++)
        #pragma unroll
        for (int b = 0; b < 4; b++)
            atomicAdd(&Gout[(tr4 + a) * DD + (tc4 + b)], m[a][b]);
    if (t < DD) {
        float ss = 0.0f;
        for (int n = 0; n < RPB; n++) ss += sH[n][t];
        atomicAdd(&sout[t], ss);
    }
}

template <typename T>
__global__ __launch_bounds__(NT) void lift_kernel(
    const int* __restrict__ flag,
    const void* __restrict__ x, const void* __restrict__ lw, const void* __restrict__ lb,
    float* __restrict__ h, float* __restrict__ Gout, float* __restrict__ sout)
{
    if (flag[0] != Acc<T>::tag) return;
    __shared__ float sH[RPB][SHP];

    const int t = threadIdx.x;
    const int row0 = blockIdx.x * RPB;
    const int bb = row0 >> 12;
    const int tr4 = (t >> 4) << 2;
    const int tc4 = (t & 15) << 2;
    const int ra2 = (t >> 4) << 1;

    #pragma unroll
    for (int a = 0; a < 2; a++) {
        const int gr = row0 + ra2 + a;
        float x0 = Acc<T>::ld(x, gr * 3 + 0);
        float x1 = Acc<T>::ld(x, gr * 3 + 1);
        float x2 = Acc<T>::ld(x, gr * 3 + 2);
        float o[4];
        #pragma unroll
        for (int b = 0; b < 4; b++) {
            int c = tc4 + b;
            o[b] = Acc<T>::ld(lb, c) + x0 * Acc<T>::ld(lw, c)
                 + x1 * Acc<T>::ld(lw, DD + c) + x2 * Acc<T>::ld(lw, 2 * DD + c);
        }
        float4 o4 = make_float4(o[0], o[1], o[2], o[3]);
        *(float4*)&sH[ra2 + a][tc4] = o4;
        *(float4*)(h + (size_t)gr * DD + tc4) = o4;
    }
    __syncthreads();
    accum_G(sH, t, tr4, tc4, Gout + bb * DD * DD, sout + bb * DD);
}

template <typename T>
__global__ __launch_bounds__(NT) void layer_kernel(
    const int* __restrict__ flag,
    float* __restrict__ h, const float* __restrict__ Gin, const float* __restrict__ sin,
    const void* __restrict__ wq, const void* __restrict__ bq,
    const void* __restrict__ wb, const void* __restrict__ bbv,
    const void* __restrict__ wk, const void* __restrict__ bk,
    const void* __restrict__ wv, const void* __restrict__ bv,
    float* __restrict__ Gout, float* __restrict__ sout,
    const void* __restrict__ pw, const void* __restrict__ pb,
    void* __restrict__ out, int is_last)
{
    if (flag[0] != Acc<T>::tag) return;

    __shared__ float A[DD][DD];
    __shared__ float B[DD][DD];
    __shared__ float C[DD][DD];
    __shared__ float sH[RPB][SHP];
    __shared__ float sS[DD], su[DD], beff[DD];

    const int t = threadIdx.x;
    const int row0 = blockIdx.x * RPB;
    const int bb = row0 >> 12;
    const int tr4 = (t >> 4) << 2;
    const int tc4 = (t & 15) << 2;
    const int ra2 = (t >> 4) << 1;

    // S0: stage A <- G (fp32), B <- Wv, sH <- h tile, sS <- s
    for (int i = t; i < DD * DD; i += NT) {
        A[i >> 6][i & 63] = Gin[bb * DD * DD + i];
        B[i >> 6][i & 63] = Acc<T>::ld(wv, i);
    }
    {
        const float4* hp = (const float4*)(h + (size_t)row0 * DD);
        for (int i = t; i < RPB * 16; i += NT)
            *(float4*)&sH[i >> 4][(i & 15) << 2] = hp[i];
    }
    if (t < DD) sS[t] = sin[bb * DD + t];
    __syncthreads();

    // S1: C = T' = G.Wv + s bv^T (G symmetric: read A[e][row]); su = s^T Wv + N bv
    {
        float acc[4][4];
        #pragma unroll
        for (int a = 0; a < 4; a++)
            #pragma unroll
            for (int b = 0; b < 4; b++) acc[a][b] = 0.0f;
        for (int e = 0; e < DD; e++) {
            float4 ga = *(const float4*)&A[e][tr4];
            float4 wv4 = *(const float4*)&B[e][tc4];
            float g[4] = {ga.x, ga.y, ga.z, ga.w};
            float w[4] = {wv4.x, wv4.y, wv4.z, wv4.w};
            #pragma unroll
            for (int a = 0; a < 4; a++)
                #pragma unroll
                for (int b = 0; b < 4; b++) acc[a][b] += g[a] * w[b];
        }
        #pragma unroll
        for (int a = 0; a < 4; a++) {
            float sa = sS[tr4 + a];
            #pragma unroll
            for (int b = 0; b < 4; b++)
                C[tr4 + a][tc4 + b] = acc[a][b] + sa * Acc<T>::ld(bv, tc4 + b);
        }
        if (t < DD) {
            float uu = 0.0f;
            for (int d = 0; d < DD; d++) uu += sS[d] * B[d][t];
            su[t] = uu + (float)NN * Acc<T>::ld(bv, t);
        }
    }
    __syncthreads();

    // S2: stage A <- Wk
    for (int i = t; i < DD * DD; i += NT) A[i >> 6][i & 63] = Acc<T>::ld(wk, i);
    __syncthreads();

    // S3: M = Wk^T.C + bk su^T  -> B (Wv dead)
    {
        float acc[4][4];
        #pragma unroll
        for (int a = 0; a < 4; a++)
            #pragma unroll
            for (int b = 0; b < 4; b++) acc[a][b] = 0.0f;
        for (int d = 0; d < DD; d++) {
            float4 ka = *(const float4*)&A[d][tr4];
            float4 tv = *(const float4*)&C[d][tc4];
            float k[4] = {ka.x, ka.y, ka.z, ka.w};
            float tt[4] = {tv.x, tv.y, tv.z, tv.w};
            #pragma unroll
            for (int a = 0; a < 4; a++)
                #pragma unroll
                for (int b = 0; b < 4; b++) acc[a][b] += k[a] * tt[b];
        }
        #pragma unroll
        for (int a = 0; a < 4; a++) {
            float bka = Acc<T>::ld(bk, tr4 + a);
            #pragma unroll
            for (int b = 0; b < 4; b++)
                B[tr4 + a][tc4 + b] = acc[a][b] + bka * su[tc4 + b];
        }
    }
    __syncthreads();

    // S4: stage A <- Wq
    for (int i = t; i < DD * DD; i += NT) A[i >> 6][i & 63] = Acc<T>::ld(wq, i);
    __syncthreads();

    // S5: C = weff = Wb + C0 * Wq.M ; beff = bb + C0 * bq.M   (C's T' dead)
    {
        float acc[4][4];
        #pragma unroll
        for (int a = 0; a < 4; a++)
            #pragma unroll
            for (int b = 0; b < 4; b++) acc[a][b] = 0.0f;
        for (int e = 0; e < DD; e++) {
            float wqa[4];
            #pragma unroll
            for (int a = 0; a < 4; a++) wqa[a] = A[tr4 + a][e];  // 4-way bank alias, ~free
            float4 m4 = *(const float4*)&B[e][tc4];
            float mm[4] = {m4.x, m4.y, m4.z, m4.w};
            #pragma unroll
            for (int a = 0; a < 4; a++)
                #pragma unroll
                for (int b = 0; b < 4; b++) acc[a][b] += wqa[a] * mm[b];
        }
        #pragma unroll
        for (int a = 0; a < 4; a++)
            #pragma unroll
            for (int b = 0; b < 4; b++)
                C[tr4 + a][tc4 + b] =
                    Acc<T>::ld(wb, (tr4 + a) * DD + tc4 + b) + C0F * acc[a][b];
        if (t < DD) {
            float s5 = 0.0f;
            for (int e = 0; e < DD; e++) s5 += Acc<T>::ld(bq, e) * B[e][t];
            beff[t] = Acc<T>::ld(bbv, t) + C0F * s5;
        }
    }
    __syncthreads();

    // S6: h' = gelu(h.weff + beff)  (2 rows x 4 cols per thread)
    float o[2][4];
    {
        float acc[2][4];
        #pragma unroll
        for (int a = 0; a < 2; a++)
            #pragma unroll
            for (int b = 0; b < 4; b++) acc[a][b] = 0.0f;
        for (int d = 0; d < DD; d++) {
            float h0 = sH[ra2 + 0][d];
            float h1 = sH[ra2 + 1][d];
            float4 w4 = *(const float4*)&C[d][tc4];
            float w[4] = {w4.x, w4.y, w4.z, w4.w};
            #pragma unroll
            for (int b = 0; b < 4; b++) { acc[0][b] += h0 * w[b]; acc[1][b] += h1 * w[b]; }
        }
        #pragma unroll
        for (int a = 0; a < 2; a++)
            #pragma unroll
            for (int b = 0; b < 4; b++)
                o[a][b] = gelu_exact(acc[a][b] + beff[tc4 + b]);
    }

    if (is_last) {
        float p[2] = {0.0f, 0.0f};
        #pragma unroll
        for (int a = 0; a < 2; a++)
            #pragma unroll
            for (int b = 0; b < 4; b++) p[a] += o[a][b] * Acc<T>::ld(pw, tc4 + b);
        #pragma unroll
        for (int sft = 1; sft < 16; sft <<= 1) {
            p[0] += __shfl_xor(p[0], sft);
            p[1] += __shfl_xor(p[1], sft);
        }
        if ((t & 15) == 0) {
            float pbv = Acc<T>::ld(pb, 0);
            Acc<T>::st(out, row0 + ra2 + 0, p[0] + pbv);
            Acc<T>::st(out, row0 + ra2 + 1, p[1] + pbv);
        }
        return;
    }

    __syncthreads();   // all sH reads done before overwrite
    #pragma unroll
    for (int a = 0; a < 2; a++) {
        float4 o4 = make_float4(o[a][0], o[a][1], o[a][2], o[a][3]);
        *(float4*)&sH[ra2 + a][tc4] = o4;
        *(float4*)(h + (size_t)(row0 + ra2 + a) * DD + tc4) = o4;
    }
    __syncthreads();

    accum_G(sH, t, tr4, tc4, Gout + bb * DD * DD, sout + bb * DD);
}

template <typename T>
static void launch_pipeline(const int* flag, void* const* d_in, void* d_out,
                            float* h, float* G, float* s, hipStream_t stream)
{
    const void* x    = d_in[0];
    const void* lw   = d_in[1];
    const void* lb   = d_in[2];
    const char* blkw = (const char*)d_in[3];
    const char* blkb = (const char*)d_in[4];
    const char* qw   = (const char*)d_in[5];
    const char* qb   = (const char*)d_in[6];
    const char* kw   = (const char*)d_in[7];
    const char* kb   = (const char*)d_in[8];
    const char* vw   = (const char*)d_in[9];
    const char* vb   = (const char*)d_in[10];
    const void* pw   = d_in[11];
    const void* pb   = d_in[12];
    const size_t esz = (Acc<T>::tag == 1) ? 2 : 4;

    lift_kernel<T><<<NGRID, NT, 0, stream>>>(flag, x, lw, lb, h, G, s);
    for (int i = 0; i < NLAYER; i++) {
        const int last = (i == NLAYER - 1);
        layer_kernel<T><<<NGRID, NT, 0, stream>>>(
            flag, h, G + i * NB * DD * DD, s + i * NB * DD,
            qw + (size_t)i * DD * DD * esz, qb + (size_t)i * DD * esz,
            blkw + (size_t)i * DD * DD * esz, blkb + (size_t)i * DD * esz,
            kw + (size_t)i * DD * DD * esz, kb + (size_t)i * DD * esz,
            vw + (size_t)i * DD * DD * esz, vb + (size_t)i * DD * esz,
            last ? nullptr : (G + (i + 1) * NB * DD * DD),
            last ? nullptr : (s + (i + 1) * NB * DD),
            pw, pb, d_out, last);
    }
}

extern "C" void kernel_launch(void* const* d_in, const int* in_sizes, int n_in,
                              void* d_out, int out_size, void* d_ws, size_t ws_size,
                              hipStream_t stream)
{
    float* h = (float*)d_ws;                                  // [2][4096][64] fp32
    float* G = h + (size_t)NB * NN * DD;                      // [4][2][64][64] fp32
    float* s = G + (size_t)NLAYER * NB * DD * DD;             // [4][2][64] fp32
    int* flag = (int*)(s + (size_t)NLAYER * NB * DD);

    hipMemsetAsync(G, 0, (size_t)(NLAYER * NB * DD * DD + NLAYER * NB * DD) * sizeof(float), stream);
    detect_kernel<<<1, NT, 0, stream>>>((const unsigned int*)d_in[0], flag);

    launch_pipeline<float>(flag, d_in, d_out, h, G, s, stream);
    launch_pipeline<bf16>(flag, d_in, d_out, h, G, s, stream);
}